// Round 1
// baseline (1277.293 us; speedup 1.0000x reference)
//
#include <hip/hip_runtime.h>

// Problem constants
#define BB 256
#define SS 512
#define DD 128

__device__ __forceinline__ float sigf(float v)  { return 1.0f / (1.0f + __expf(-v)); }
__device__ __forceinline__ float tanhf_(float v){ return 1.0f - 2.0f / (__expf(2.0f * v) + 1.0f); }

// ---------------------------------------------------------------------------
// Kernel A: precompute additive tables (fold corr/qd/cd embedding matmul parts)
//   Ck[c][j]  = b_ki[j] + sum_i E_corr[c][i] * W_ki[128+i][j]   (2 x 128)
//   Cp1[c][j] = b_p1[j] + sum_i E_corr[c][i] * W_p1[128+i][j]   (2 x 128)
//   Cp2[c][j] = b_p2[j] + sum_i E_corr[c][i] * W_p2[128+i][j]   (2 x 128)
//   Qk[q][j]  =           sum_i E_qd[q][i]   * W_ki[256+i][j]   (101 x 128)
//   Cdk[d][j] =           sum_i E_cd[d][i]   * W_ki[384+i][j]   (101 x 128)
// ---------------------------------------------------------------------------
__global__ void dimkt_tables(const float* __restrict__ E_corr,
                             const float* __restrict__ E_qd,
                             const float* __restrict__ E_cd,
                             const float* __restrict__ W_ki,
                             const float* __restrict__ W_p1,
                             const float* __restrict__ W_p2,
                             const float* __restrict__ b_ki,
                             const float* __restrict__ b_p1,
                             const float* __restrict__ b_p2,
                             float* __restrict__ Ck, float* __restrict__ Cp1,
                             float* __restrict__ Cp2, float* __restrict__ Qk,
                             float* __restrict__ Cdk)
{
    __shared__ float e[128];
    const int r = blockIdx.x;
    const int j = threadIdx.x;
    const float *emb, *W, *bias;
    float* op;
    if (r < 2)        { emb = E_corr + r * 128;        W = W_ki + 128 * 128; bias = b_ki;    op = Ck  + r * 128; }
    else if (r < 4)   { emb = E_corr + (r - 2) * 128;  W = W_p1 + 128 * 128; bias = b_p1;    op = Cp1 + (r - 2) * 128; }
    else if (r < 6)   { emb = E_corr + (r - 4) * 128;  W = W_p2 + 128 * 128; bias = b_p2;    op = Cp2 + (r - 4) * 128; }
    else if (r < 107) { emb = E_qd   + (r - 6) * 128;  W = W_ki + 256 * 128; bias = nullptr; op = Qk  + (r - 6) * 128; }
    else              { emb = E_cd   + (r - 107) * 128; W = W_ki + 384 * 128; bias = nullptr; op = Cdk + (r - 107) * 128; }
    e[j] = emb[j];
    __syncthreads();
    float acc = bias ? bias[j] : 0.0f;
#pragma unroll 8
    for (int i = 0; i < 128; ++i) acc = fmaf(e[i], W[i * 128 + j], acc);
    op[j] = acc;
}

// ---------------------------------------------------------------------------
// Kernel B: x = concat(E_q[q], E_c[c], E_qd[qd], E_cd[cd]) @ Wx + bx
//   M = B*S = 131072 rows, K = 512 (4 segments of 128), N = 128.
//   fp32 LDS-tiled GEMM, 128-row tile per block, 8x8 per-thread microtile.
// ---------------------------------------------------------------------------
#define AP 134   // padded LDS stride for the A tile (bank-conflict friendly)

__global__ __launch_bounds__(256, 2) void dimkt_xgemm(
    const int* __restrict__ q_seq, const int* __restrict__ c_seq,
    const int* __restrict__ qd_seq, const int* __restrict__ cd_seq,
    const float* __restrict__ E_q, const float* __restrict__ E_c,
    const float* __restrict__ E_qd, const float* __restrict__ E_cd,
    const float* __restrict__ Wx, const float* __restrict__ bx,
    float* __restrict__ xout)
{
    __shared__ float As[128 * AP];
    __shared__ float Bs[128 * 128];
    const int tid = threadIdx.x;
    const int ty = tid >> 4;     // 0..15, row group of 8
    const int tx = tid & 15;     // 0..15, col group of 8
    const int m0 = blockIdx.x * 128;

    const int*   seqs[4] = { q_seq, c_seq, qd_seq, cd_seq };
    const float* tabs[4] = { E_q,   E_c,   E_qd,   E_cd  };

    float acc[8][8];
#pragma unroll
    for (int r = 0; r < 8; ++r)
#pragma unroll
        for (int c = 0; c < 8; ++c) acc[r][c] = 0.0f;

#pragma unroll 1
    for (int s = 0; s < 4; ++s) {
        __syncthreads();
        const int*   sq = seqs[s];
        const float* tb = tabs[s];
        // stage gathered A tile: 128 rows x 128 floats (as float2)
        for (int i = tid; i < 128 * 64; i += 256) {
            int row = i >> 6;
            int c2  = (i & 63) << 1;
            int e   = sq[m0 + row];
            float2 v = *(const float2*)&tb[e * 128 + c2];
            *(float2*)&As[row * AP + c2] = v;
        }
        // stage B tile: Wx rows [s*128, s*128+128)
        for (int i = tid; i < 128 * 32; i += 256) {
            int k  = i >> 5;
            int c4 = (i & 31) << 2;
            *(float4*)&Bs[k * 128 + c4] = *(const float4*)&Wx[(s * 128 + k) * 128 + c4];
        }
        __syncthreads();
#pragma unroll 4
        for (int k = 0; k < 128; ++k) {
            float a[8];
#pragma unroll
            for (int r = 0; r < 8; ++r) a[r] = As[(ty * 8 + r) * AP + k];
            float4 b0 = *(const float4*)&Bs[k * 128 + tx * 8];
            float4 b1 = *(const float4*)&Bs[k * 128 + tx * 8 + 4];
            float bb[8] = { b0.x, b0.y, b0.z, b0.w, b1.x, b1.y, b1.z, b1.w };
#pragma unroll
            for (int r = 0; r < 8; ++r)
#pragma unroll
                for (int c = 0; c < 8; ++c)
                    acc[r][c] = fmaf(a[r], bb[c], acc[r][c]);
        }
    }

    float4 bx0 = *(const float4*)&bx[tx * 8];
    float4 bx1 = *(const float4*)&bx[tx * 8 + 4];
    float bxa[8] = { bx0.x, bx0.y, bx0.z, bx0.w, bx1.x, bx1.y, bx1.z, bx1.w };
#pragma unroll
    for (int r = 0; r < 8; ++r) {
        int row = m0 + ty * 8 + r;
        float4 o0 = make_float4(acc[r][0] + bxa[0], acc[r][1] + bxa[1],
                                acc[r][2] + bxa[2], acc[r][3] + bxa[3]);
        float4 o1 = make_float4(acc[r][4] + bxa[4], acc[r][5] + bxa[5],
                                acc[r][6] + bxa[6], acc[r][7] + bxa[7]);
        *(float4*)&xout[row * 128 + tx * 8]     = o0;
        *(float4*)&xout[row * 128 + tx * 8 + 4] = o1;
    }
}

// ---------------------------------------------------------------------------
// Kernel C: the sequential scan. One block (256 threads, 4 waves) per batch
// element; one block per CU. The 5 scan matrices (W_s1, W_s2, W_p1[:128],
// W_p2[:128], W_ki[:128]) live in per-thread registers: thread (rg = wave id,
// cg = lane) owns rows [32*rg, 32*rg+32) of columns {2cg, 2cg+1} of each
// matrix (64 fp32 weights per matrix per thread = 320 VGPRs).
// Input vectors (d, h, sdf) broadcast via LDS; column partials reduced via
// small LDS buffers. 4 barriers / step.
// ---------------------------------------------------------------------------
__global__ __launch_bounds__(256, 1) void dimkt_scan(
    const float* __restrict__ x,
    const int* __restrict__ corr_seq, const int* __restrict__ qd_seq,
    const int* __restrict__ cd_seq,
    const float* __restrict__ W_s1, const float* __restrict__ b_s1,
    const float* __restrict__ W_s2, const float* __restrict__ b_s2,
    const float* __restrict__ W_p1, const float* __restrict__ W_p2,
    const float* __restrict__ W_ki,
    const float* __restrict__ Ck, const float* __restrict__ Cp1,
    const float* __restrict__ Cp2, const float* __restrict__ Qk,
    const float* __restrict__ Cdk,
    const float* __restrict__ h0, float* __restrict__ out)
{
    __shared__ float h_lds[128], d_lds[128], sdf_lds[128], prod_lds[128];
    __shared__ float pA1[512], pA2[512], pKG[512], pP1[512], pP2[512];

    const int tid = threadIdx.x;
    const int b   = blockIdx.x;
    const int rg  = tid >> 6;        // wave id: row group of 32
    const int cg  = tid & 63;        // lane: column pair
    const int j0  = cg * 2;
    const int base = b * SS;         // flattened (b, t) row base

    // --- load register-resident weights -------------------------------
    float2 w1[32], w2[32], wp1[32], wp2[32], wk[32];
#pragma unroll
    for (int k = 0; k < 32; ++k) {
        int i = rg * 32 + k;
        w1[k]  = *(const float2*)&W_s1[i * 128 + j0];
        w2[k]  = *(const float2*)&W_s2[i * 128 + j0];
        wp1[k] = *(const float2*)&W_p1[i * 128 + j0];
        wp2[k] = *(const float2*)&W_p2[i * 128 + j0];
        wk[k]  = *(const float2*)&W_ki[i * 128 + j0];
    }

    float xreg = 0.0f, xnext = 0.0f;
    float tCk = 0.0f, tQk = 0.0f, tCdk = 0.0f, tCp1 = 0.0f, tCp2 = 0.0f;
    float nCk = 0.0f, nQk = 0.0f, nCdk = 0.0f, nCp1 = 0.0f, nCp2 = 0.0f;
    float bs1 = 0.0f, bs2 = 0.0f, greg = 0.0f;

    if (tid < 128) {
        int j = tid;
        h_lds[j] = h0[b * 128 + j];
        bs1 = b_s1[j];
        bs2 = b_s2[j];
        xreg = x[(base + 0) * 128 + j];
        int c0 = corr_seq[base], q0 = qd_seq[base], e0 = cd_seq[base];
        tCk  = Ck [c0 * 128 + j];
        tQk  = Qk [q0 * 128 + j];
        tCdk = Cdk[e0 * 128 + j];
        tCp1 = Cp1[c0 * 128 + j];
        tCp2 = Cp2[c0 * 128 + j];
    }
    __syncthreads();

    for (int t = 0; t < 511; ++t) {
        // ---- Stage A: d = x_t - h, prod = x_t * h; prefetch x_{t+1} ----
        if (tid < 128) {
            int j = tid;
            float hv = h_lds[j];
            d_lds[j]    = xreg - hv;
            prod_lds[j] = xreg * hv;
            xnext = x[(base + t + 1) * 128 + j];
        }
        __syncthreads();   // B0

        // ---- Stage B: phase-1 matvecs (a1 = d@Ws1, a2 = d@Ws2, kg = h@Wki_h)
        {
            float a10 = 0.f, a11 = 0.f, a20 = 0.f, a21 = 0.f, k0 = 0.f, k1 = 0.f;
#pragma unroll
            for (int kk = 0; kk < 8; ++kk) {
                const int k4 = kk * 4;
                float4 dv = *(const float4*)&d_lds[rg * 32 + k4];
                float4 hv = *(const float4*)&h_lds[rg * 32 + k4];
                a10 = fmaf(dv.x, w1[k4 + 0].x, a10); a11 = fmaf(dv.x, w1[k4 + 0].y, a11);
                a20 = fmaf(dv.x, w2[k4 + 0].x, a20); a21 = fmaf(dv.x, w2[k4 + 0].y, a21);
                k0  = fmaf(hv.x, wk[k4 + 0].x, k0);  k1  = fmaf(hv.x, wk[k4 + 0].y, k1);
                a10 = fmaf(dv.y, w1[k4 + 1].x, a10); a11 = fmaf(dv.y, w1[k4 + 1].y, a11);
                a20 = fmaf(dv.y, w2[k4 + 1].x, a20); a21 = fmaf(dv.y, w2[k4 + 1].y, a21);
                k0  = fmaf(hv.y, wk[k4 + 1].x, k0);  k1  = fmaf(hv.y, wk[k4 + 1].y, k1);
                a10 = fmaf(dv.z, w1[k4 + 2].x, a10); a11 = fmaf(dv.z, w1[k4 + 2].y, a11);
                a20 = fmaf(dv.z, w2[k4 + 2].x, a20); a21 = fmaf(dv.z, w2[k4 + 2].y, a21);
                k0  = fmaf(hv.z, wk[k4 + 2].x, k0);  k1  = fmaf(hv.z, wk[k4 + 2].y, k1);
                a10 = fmaf(dv.w, w1[k4 + 3].x, a10); a11 = fmaf(dv.w, w1[k4 + 3].y, a11);
                a20 = fmaf(dv.w, w2[k4 + 3].x, a20); a21 = fmaf(dv.w, w2[k4 + 3].y, a21);
                k0  = fmaf(hv.w, wk[k4 + 3].x, k0);  k1  = fmaf(hv.w, wk[k4 + 3].y, k1);
            }
            *(float2*)&pA1[rg * 128 + j0] = make_float2(a10, a11);
            *(float2*)&pA2[rg * 128 + j0] = make_float2(a20, a21);
            *(float2*)&pKG[rg * 128 + j0] = make_float2(k0, k1);
        }
        __syncthreads();   // B1

        // ---- Stage C: reduce phase-1, nonlinearities; y-reduce on wave 2 ----
        if (tid < 128) {
            int j = tid;
            float a1 = pA1[j] + pA1[128 + j] + pA1[256 + j] + pA1[384 + j] + bs1;
            float a2 = pA2[j] + pA2[128 + j] + pA2[256 + j] + pA2[384 + j] + bs2;
            float kg = pKG[j] + pKG[128 + j] + pKG[256 + j] + pKG[384 + j]
                     + tCk + tQk + tCdk;
            sdf_lds[j] = sigf(a1) * tanhf_(a2);
            greg = sigf(kg);
            // prefetch next-step tables
            int nt = t + 1;
            int c1 = corr_seq[base + nt], q1 = qd_seq[base + nt], e1 = cd_seq[base + nt];
            nCk  = Ck [c1 * 128 + j];
            nQk  = Qk [q1 * 128 + j];
            nCdk = Cdk[e1 * 128 + j];
            nCp1 = Cp1[c1 * 128 + j];
            nCp2 = Cp2[c1 * 128 + j];
        } else if (tid < 192) {
            if (t > 0) {
                int lane = tid - 128;
                float2 pv = *(const float2*)&prod_lds[lane * 2];
                float s = pv.x + pv.y;
#pragma unroll
                for (int m = 32; m; m >>= 1) s += __shfl_xor(s, m);
                if (lane == 0) out[base + t - 1] = sigf(s);
            }
        }
        __syncthreads();   // B2

        // ---- Stage D: phase-2 matvecs (p1 = sdf@Wp1_h, p2 = sdf@Wp2_h) ----
        {
            float p10 = 0.f, p11 = 0.f, p20 = 0.f, p21 = 0.f;
#pragma unroll
            for (int kk = 0; kk < 8; ++kk) {
                const int k4 = kk * 4;
                float4 sv = *(const float4*)&sdf_lds[rg * 32 + k4];
                p10 = fmaf(sv.x, wp1[k4 + 0].x, p10); p11 = fmaf(sv.x, wp1[k4 + 0].y, p11);
                p20 = fmaf(sv.x, wp2[k4 + 0].x, p20); p21 = fmaf(sv.x, wp2[k4 + 0].y, p21);
                p10 = fmaf(sv.y, wp1[k4 + 1].x, p10); p11 = fmaf(sv.y, wp1[k4 + 1].y, p11);
                p20 = fmaf(sv.y, wp2[k4 + 1].x, p20); p21 = fmaf(sv.y, wp2[k4 + 1].y, p21);
                p10 = fmaf(sv.z, wp1[k4 + 2].x, p10); p11 = fmaf(sv.z, wp1[k4 + 2].y, p11);
                p20 = fmaf(sv.z, wp2[k4 + 2].x, p20); p21 = fmaf(sv.z, wp2[k4 + 2].y, p21);
                p10 = fmaf(sv.w, wp1[k4 + 3].x, p10); p11 = fmaf(sv.w, wp1[k4 + 3].y, p11);
                p20 = fmaf(sv.w, wp2[k4 + 3].x, p20); p21 = fmaf(sv.w, wp2[k4 + 3].y, p21);
            }
            *(float2*)&pP1[rg * 128 + j0] = make_float2(p10, p11);
            *(float2*)&pP2[rg * 128 + j0] = make_float2(p20, p21);
        }
        __syncthreads();   // B3

        // ---- Stage E: reduce phase-2, update h, rotate prefetches ----
        if (tid < 128) {
            int j = tid;
            float p1 = pP1[j] + pP1[128 + j] + pP1[256 + j] + pP1[384 + j] + tCp1;
            float p2 = pP2[j] + pP2[128 + j] + pP2[256 + j] + pP2[384 + j] + tCp2;
            float pka = sigf(p1) * tanhf_(p2);
            float hv = h_lds[j];
            float hn = greg * hv + (1.0f - greg) * pka;
            h_lds[j] = hn;
            xreg = xnext;
            tCk = nCk; tQk = nQk; tCdk = nCdk; tCp1 = nCp1; tCp2 = nCp2;
        }
    }

    // ---- epilogue: y_510 = sigmoid(x_511 . h_511); y[:,511] = 0 ----
    if (tid < 128) prod_lds[tid] = xreg * h_lds[tid];
    __syncthreads();
    if (tid >= 128 && tid < 192) {
        int lane = tid - 128;
        float2 pv = *(const float2*)&prod_lds[lane * 2];
        float s = pv.x + pv.y;
#pragma unroll
        for (int m = 32; m; m >>= 1) s += __shfl_xor(s, m);
        if (lane == 0) out[base + 510] = sigf(s);
    }
    if (tid == 0) out[base + 511] = 0.0f;
}

// ---------------------------------------------------------------------------
extern "C" void kernel_launch(void* const* d_in, const int* in_sizes, int n_in,
                              void* d_out, int out_size, void* d_ws, size_t ws_size,
                              hipStream_t stream) {
    const int*   q_seq    = (const int*)d_in[0];
    const int*   c_seq    = (const int*)d_in[1];
    const int*   qd_seq   = (const int*)d_in[2];
    const int*   cd_seq   = (const int*)d_in[3];
    const int*   corr_seq = (const int*)d_in[4];
    const float* E_q    = (const float*)d_in[5];
    const float* E_c    = (const float*)d_in[6];
    const float* E_qd   = (const float*)d_in[7];
    const float* E_cd   = (const float*)d_in[8];
    const float* E_corr = (const float*)d_in[9];
    const float* Wx     = (const float*)d_in[10];
    const float* bx     = (const float*)d_in[11];
    const float* W_s1   = (const float*)d_in[12];
    const float* b_s1   = (const float*)d_in[13];
    const float* W_s2   = (const float*)d_in[14];
    const float* b_s2   = (const float*)d_in[15];
    const float* W_p1   = (const float*)d_in[16];
    const float* b_p1   = (const float*)d_in[17];
    const float* W_p2   = (const float*)d_in[18];
    const float* b_p2   = (const float*)d_in[19];
    const float* W_ki   = (const float*)d_in[20];
    const float* b_ki   = (const float*)d_in[21];
    const float* h0     = (const float*)d_in[22];
    float* out = (float*)d_out;

    // workspace carve-up (fp32): x [B*S*128], then the 5 tables
    float* xbuf = (float*)d_ws;                 // 16,777,216 floats
    float* Ck   = xbuf + (size_t)BB * SS * DD;  // 2 x 128
    float* Cp1  = Ck  + 256;                    // 2 x 128
    float* Cp2  = Cp1 + 256;                    // 2 x 128
    float* Qk   = Cp2 + 256;                    // 101 x 128
    float* Cdk  = Qk  + 101 * 128;              // 101 x 128

    dimkt_tables<<<208, 128, 0, stream>>>(E_corr, E_qd, E_cd, W_ki, W_p1, W_p2,
                                          b_ki, b_p1, b_p2, Ck, Cp1, Cp2, Qk, Cdk);

    dimkt_xgemm<<<(BB * SS) / 128, 256, 0, stream>>>(q_seq, c_seq, qd_seq, cd_seq,
                                                     E_q, E_c, E_qd, E_cd, Wx, bx, xbuf);

    dimkt_scan<<<BB, 256, 0, stream>>>(xbuf, corr_seq, qd_seq, cd_seq,
                                       W_s1, b_s1, W_s2, b_s2, W_p1, W_p2, W_ki,
                                       Ck, Cp1, Cp2, Qk, Cdk, h0, out);
}